// Round 2
// baseline (836.949 us; speedup 1.0000x reference)
//
#include <hip/hip_runtime.h>
#include <math.h>

// Problem constants (reference: N=32, K=16, BINS=100, DIM=2, sample_size=100)
#define NBINS 100
#define NB    101   // BINS+1
#define NN    32
#define KDIM  16
#define NT    99    // sample_size-1

// ws layout (float offsets)
#define OFF_B    0        // Btil 101x101 (f32)
#define OFF_S    10201    // s[b][j][d] 101*16*2
#define OFF_T    13433    // t[b][j][d]
#define OFF_Q    16665    // Q = C*U  32*16
#define OFF_C    17177    // c_j = sigma^-2 * mu_j  (16)
#define OFF_P    17193    // params: [0]=sigma_sq_inv [1]=-0.5/ls^2
#define OFF_XL   17197    // x_last 64

// ---------------------------------------------------------------- K1: setup
// Single wave (64 lanes): Btil, x_last, G_C -> Jacobi eig (f64) -> Q, c_j, s.
// All barriers are single-wave (near-free s_barrier).
__global__ __launch_bounds__(64) void k1_setup(
    const float* __restrict__ x0, const float* __restrict__ v,
    const float* __restrict__ sigma_in, const float* __restrict__ x0c_in,
    const float* __restrict__ ls_in, const float* __restrict__ Cq,
    float* __restrict__ ws)
{
  const int tid = threadIdx.x;
  const float ls = ls_in[0];
  const float inv2ls2 = -0.5f / (ls * ls);
  const float x0c = x0c_in[0];
  float sig = fmaxf(sigma_in[0], 0.05f);           // clip(sigma, 5/BINS)
  const float sigma_sq_inv = 1.0f / (sig * sig);

  __shared__ double A[16][16], At[16][16], V[16][16];
  __shared__ double csC[8], csS[8];
  __shared__ int prP[8], prQ[8];
  __shared__ float Qs[NN * KDIM];
  __shared__ float CqS[NN * KDIM];
  __shared__ float xv[NB * 64];                    // x0v staged (25.9 KB)

  // Btil = Bk + jitter*I  (block-diag: [0,0]=x0_c^2, [1:,1:]=RBF gram)
  for (int idx = tid; idx < NB * NB; idx += 64) {
    int i = idx / NB, j = idx % NB;
    float val;
    if (i == 0 || j == 0) {
      val = (i == 0 && j == 0) ? (x0c * x0c + 1e-5f) : 0.0f;
    } else {
      float dd = (float)(j - i) * 0.01f;
      val = expf(dd * dd * inv2ls2);
      if (i == j) val += 1e-5f;
    }
    ws[OFF_B + idx] = val;
  }

  // x_last = x0 + 0.01 * sum_b v   (exactly 64 outputs, one per lane)
  {
    float acc = 0.f;
    for (int p = 0; p < NBINS; ++p) acc += v[p * 64 + tid];
    ws[OFF_XL + tid] = x0[tid] + 0.01f * acc;
  }

  // stage Cq and x0v
  for (int idx = tid; idx < NN * KDIM; idx += 64) CqS[idx] = Cq[idx];
  for (int idx = tid; idx < NB * 64; idx += 64)
    xv[idx] = (idx < 64) ? x0[idx] : v[idx - 64];
  __syncthreads();

  // G_C = Cq^T Cq (f64), V = I
  for (int it = tid; it < 256; it += 64) {
    int k1 = it >> 4, k2 = it & 15;
    double acc = 0.0;
    for (int n = 0; n < NN; ++n)
      acc += (double)CqS[n * 16 + k1] * (double)CqS[n * 16 + k2];
    A[k1][k2] = acc;
    V[k1][k2] = (k1 == k2) ? 1.0 : 0.0;
  }
  __syncthreads();

  // Jacobi, 8 sweeps x 15 round-robin rounds
  for (int sweep = 0; sweep < 8; ++sweep)
  for (int r = 0; r < 15; ++r) {
    if (tid < 8) {
      int i = tid;
      int p = (i == 0) ? 0 : (1 + ((i - 1 + r) % 15));
      int q = 1 + ((14 - i + r) % 15);
      if (p > q) { int tt = p; p = q; q = tt; }
      prP[i] = p; prQ[i] = q;
      double app = A[p][p], aqq = A[q][q], apq = A[p][q];
      double c = 1.0, s = 0.0;
      if (fabs(apq) > 1e-300) {
        double th = (aqq - app) / (2.0 * apq);
        double t_ = ((th >= 0.0) ? 1.0 : -1.0) / (fabs(th) + sqrt(th * th + 1.0));
        c = 1.0 / sqrt(t_ * t_ + 1.0);
        s = t_ * c;
      }
      csC[i] = c; csS[i] = s;
    }
    __syncthreads();
    for (int it = tid; it < 128; it += 64) {       // row phase: At = J^T A
      int i = it >> 4, col = it & 15;
      int p = prP[i], q = prQ[i];
      double c = csC[i], s = csS[i];
      double ap = A[p][col], aq = A[q][col];
      At[p][col] = c * ap - s * aq;
      At[q][col] = s * ap + c * aq;
    }
    __syncthreads();
    for (int it = tid; it < 256; it += 64) {       // col phase + V update
      int t2 = it & 127;
      int i = t2 >> 4, row = t2 & 15;
      int p = prP[i], q = prQ[i];
      double c = csC[i], s = csS[i];
      if (it < 128) {
        double ap = At[row][p], aq = At[row][q];
        A[row][p] = c * ap - s * aq;
        A[row][q] = s * ap + c * aq;
      } else {
        double vp = V[row][p], vq = V[row][q];
        V[row][p] = c * vp - s * vq;
        V[row][q] = s * vp + c * vq;
      }
    }
    __syncthreads();
  }

  if (tid < 16) {
    double mu = A[tid][tid];
    if (mu < 0.0) mu = 0.0;
    ws[OFF_C + tid] = (float)((double)sigma_sq_inv * mu);
  }
  if (tid == 0) {
    ws[OFF_P + 0] = sigma_sq_inv;
    ws[OFF_P + 1] = inv2ls2;
  }
  // Q = C * U_C
  for (int it = tid; it < NN * KDIM; it += 64) {
    int n = it >> 4, jq = it & 15;
    double acc = 0.0;
    for (int k2 = 0; k2 < 16; ++k2) acc += (double)CqS[n * 16 + k2] * V[k2][jq];
    Qs[it] = (float)acc;
    ws[OFF_Q + it] = (float)acc;
  }
  __syncthreads();

  // s[b][j][d] = sum_n Q[n][j] * x0v[b][n][d]   (1616 (b,j) pairs, d=0,1)
  for (int it = tid; it < NB * KDIM; it += 64) {
    int b = it >> 4, jq = it & 15;
    float a0 = 0.f, a1 = 0.f;
    for (int n = 0; n < NN; ++n) {
      float q = Qs[n * 16 + jq];
      a0 += q * xv[b * 64 + 2 * n];
      a1 += q * xv[b * 64 + 2 * n + 1];
    }
    ws[OFF_S + (b * 16 + jq) * 2 + 0] = a0;
    ws[OFF_S + (b * 16 + jq) * 2 + 1] = a1;
  }
}

// ------------------------------------------- K2: per-eigenvalue SPD solve
// One wave per block, one block per eigen-system j.
// M = I + c_j*Btil (f64 LDS), rhs = Btil*s_j, full-square Cholesky, solves.
__global__ __launch_bounds__(64) void k2_chol(float* __restrict__ ws)
{
  extern __shared__ double sm[];
  double* Ms   = sm;                 // 101*102
  double* invd = Ms + NB * 102;      // 101
  double* rhs  = invd + NB;          // 2*101  (rhs -> y -> t, in place)
  float*  sbuf = (float*)(rhs + 2 * NB);  // 202 f32

  const int tid = threadIdx.x;
  const int j = blockIdx.x;
  const double cj = (double)ws[OFF_C + j];

  for (int idx = tid; idx < NB * NB; idx += 64) {
    int i = idx / NB, c_ = idx % NB;
    Ms[i * 102 + c_] = (double)ws[OFF_B + idx];
  }
  for (int idx = tid; idx < 2 * NB; idx += 64) {
    int d = idx / NB, b = idx % NB;
    sbuf[d * NB + b] = ws[OFF_S + (b * 16 + j) * 2 + d];
  }
  __syncthreads();

  // rhs = Btil * s
  for (int idx = tid; idx < 2 * NB; idx += 64) {
    int d = idx / NB, b = idx % NB;
    double acc = 0.0;
    for (int bp = 0; bp < NB; ++bp)
      acc += Ms[b * 102 + bp] * (double)sbuf[d * NB + bp];
    rhs[idx] = acc;
  }
  __syncthreads();

  // M = I + c*Btil (in place)
  for (int idx = tid; idx < NB * NB; idx += 64) {
    int i = idx / NB, c_ = idx % NB;
    double val = cj * Ms[i * 102 + c_];
    if (i == c_) val += 1.0;
    Ms[i * 102 + c_] = val;
  }
  __syncthreads();

  // Cholesky, full-square trailing update (trailing stays symmetric; the
  // never-scaled upper row k holds L[col][k]*piv_k -> row-contiguous solves).
  for (int k = 0; k < NB; ++k) {
    double piv = sqrt(Ms[k * 102 + k]);            // wave-broadcast read
    double ip = 1.0 / piv;
    if (tid == 0) { Ms[k * 102 + k] = piv; invd[k] = ip; }
    for (int r = k + 1 + tid; r < NB; r += 64)
      Ms[r * 102 + k] *= ip;
    __syncthreads();
    const int m = NB - 1 - k;
    for (int cb = 0; cb * 64 < m; ++cb) {
      int col = k + 1 + cb * 64 + tid;
      double Lc = (col < NB) ? Ms[col * 102 + k] : 0.0;
      if (col < NB) {
        for (int i = k + 1; i < NB; ++i) {
          double lik = Ms[i * 102 + k];            // same-addr broadcast
          Ms[i * 102 + col] -= lik * Lc;
        }
      }
    }
    __syncthreads();
  }

  // forward solve L y = rhs (in place; L[r][i] = Ms[i][r]*invd[i], row reads)
  for (int i = 0; i < NB; ++i) {
    double iv = invd[i];
    double y0 = rhs[i] * iv;
    double y1 = rhs[NB + i] * iv;
    if (tid == 0) { rhs[i] = y0; rhs[NB + i] = y1; }
    double f0 = y0 * iv, f1 = y1 * iv;
    for (int r = i + 1 + tid; r < NB; r += 64) {
      double m_ = Ms[i * 102 + r];
      rhs[r]      -= m_ * f0;
      rhs[NB + r] -= m_ * f1;
    }
    __syncthreads();
  }
  // backward solve L^T t = y (L[i][r] = Ms[i*102+r], r<i, row reads)
  for (int i = NB - 1; i >= 0; --i) {
    double iv = invd[i];
    double t0 = rhs[i] * iv;
    double t1 = rhs[NB + i] * iv;
    if (tid == 0) { rhs[i] = t0; rhs[NB + i] = t1; }
    for (int r = tid; r < i; r += 64) {
      double m_ = Ms[i * 102 + r];
      rhs[r]      -= m_ * t0;
      rhs[NB + r] -= m_ * t1;
    }
    __syncthreads();
  }

  for (int idx = tid; idx < 2 * NB; idx += 64) {
    int d = idx / NB, b = idx % NB;
    ws[OFF_T + (b * 16 + j) * 2 + d] = (float)rhs[idx];
  }
}

// ---------------- K3 (fused): y, Y2, Bc table, xt, intensity integral
// One block, 256 threads, dynamic LDS pools.
#define D_Q   0
#define D_C   512
#define D_T   1024     // t (3232) -> reused as av
#define D_Y   4256     // y (6464) -> overwritten by Y2
#define D_BC  10720    // Bc 99*100
#define D_XT  20620    // xt 99*64
#define D_XL  26956    // x_last 64
#define D_TOT 27020

__global__ __launch_bounds__(256) void k3_final(
    const float* __restrict__ x0, const float* __restrict__ v,
    const float* __restrict__ beta, const float* __restrict__ Cq,
    const float* __restrict__ ws, float* __restrict__ out)
{
  extern __shared__ float lds[];
  const int tid = threadIdx.x;
  const float sinv    = ws[OFF_P + 0];
  const float inv2ls2 = ws[OFF_P + 1];

  // phase 1: stage Q, Cq, t, x_last
  for (int i = tid; i < 512; i += 256) { lds[D_Q + i] = ws[OFF_Q + i]; lds[D_C + i] = Cq[i]; }
  for (int i = tid; i < 3232; i += 256) lds[D_T + i] = ws[OFF_T + i];
  if (tid < 64) lds[D_XL + tid] = ws[OFF_XL + tid];
  __syncthreads();

  // phase 2: y = sinv*x - sinv^2 * Q t
  for (int idx = tid; idx < NB * 64; idx += 256) {
    int b = idx >> 6, r = idx & 63, n = r >> 1, d = r & 1;
    float acc = 0.f;
    for (int jq = 0; jq < 16; ++jq)
      acc += lds[D_Q + n * 16 + jq] * lds[D_T + b * 32 + jq * 2 + d];
    float xval = (idx < 64) ? x0[idx] : v[idx - 64];
    lds[D_Y + idx] = sinv * xval - sinv * sinv * acc;
  }
  __syncthreads();

  // phase 3: av = C^T y (into D_T pool) ; Bc table
  for (int idx = tid; idx < NB * 32; idx += 256) {
    int b = idx >> 5, r = idx & 31, k = r >> 1, d = r & 1;
    float acc = 0.f;
    for (int n = 0; n < NN; ++n)
      acc += lds[D_C + n * 16 + k] * lds[D_Y + b * 64 + n * 2 + d];
    lds[D_T + idx] = acc;
  }
  for (int idx = tid; idx < NT * NBINS; idx += 256) {
    int t = idx / NBINS, p = idx % NBINS;
    float tst = 1.0f + (float)t * (1.0f / 99.0f);
    float dd = tst - ((float)p + 0.5f) * 0.01f;
    lds[D_BC + idx] = expf(dd * dd * inv2ls2);
  }
  __syncthreads();

  // phase 4: Y2 = C av (overwrite D_Y)
  for (int idx = tid; idx < NB * 64; idx += 256) {
    int b = idx >> 6, r = idx & 63, n = r >> 1, d = r & 1;
    float acc = 0.f;
    for (int k = 0; k < 16; ++k)
      acc += lds[D_C + n * 16 + k] * lds[D_T + b * 32 + k * 2 + d];
    lds[D_Y + idx] = acc;
  }
  __syncthreads();

  // phase 5: xt[t][n][:] = x_last + trel * sum_p Bc[t][p]*Y2[p+1][n][:]
  // thread = (tg, n): 8 t-groups x 32 n; register accumulate 13 t's.
  {
    const int n = tid & 31, tg = tid >> 5;
    float ax[13], ay[13];
    for (int s = 0; s < 13; ++s) { ax[s] = 0.f; ay[s] = 0.f; }
    for (int p = 0; p < NBINS; ++p) {
      float2 yv = *(const float2*)&lds[D_Y + (p + 1) * 64 + 2 * n];
      #pragma unroll
      for (int s = 0; s < 13; ++s) {
        int t = tg * 13 + s;
        if (t < NT) {
          float bc = lds[D_BC + t * NBINS + p];
          ax[s] += bc * yv.x;
          ay[s] += bc * yv.y;
        }
      }
    }
    float xlx = lds[D_XL + 2 * n], xly = lds[D_XL + 2 * n + 1];
    for (int s = 0; s < 13; ++s) {
      int t = tg * 13 + s;
      if (t < NT) {
        float trel = (float)t * (1.0f / 99.0f);
        lds[D_XT + t * 64 + 2 * n]     = xlx + trel * ax[s];
        lds[D_XT + t * 64 + 2 * n + 1] = xly + trel * ay[s];
      }
    }
  }
  __syncthreads();

  // phase 6: intensity integral
  for (int pair = tid; pair < NN * NN; pair += 256) {
    int i = pair >> 5, jj = pair & 31;
    float bsum = beta[i] + beta[jj];
    float acc = 0.f;
    for (int t = 0; t < NT; ++t) {
      float2 xi = *(const float2*)&lds[D_XT + t * 64 + 2 * i];
      float2 xj = *(const float2*)&lds[D_XT + t * 64 + 2 * jj];
      float dx = xi.x - xj.x, dy = xi.y - xj.y;
      float sq = fmaxf(dx * dx + dy * dy, 1e-12f);
      acc += expf(bsum - sqrtf(sq));
    }
    out[pair] = acc * (1.0f / 99.0f);
  }
}

extern "C" void kernel_launch(void* const* d_in, const int* in_sizes, int n_in,
                              void* d_out, int out_size, void* d_ws, size_t ws_size,
                              hipStream_t stream) {
  const float* x0    = (const float*)d_in[0];
  const float* v     = (const float*)d_in[1];
  const float* beta  = (const float*)d_in[2];
  const float* sigma = (const float*)d_in[3];
  const float* x0c   = (const float*)d_in[4];
  const float* ls    = (const float*)d_in[5];
  const float* Cq    = (const float*)d_in[6];
  float* out = (float*)d_out;
  float* ws  = (float*)d_ws;

  k1_setup<<<1, 64, 0, stream>>>(x0, v, sigma, x0c, ls, Cq, ws);
  const size_t smem2 = (size_t)(NB * 102 + NB + 2 * NB) * sizeof(double)
                     + (size_t)(2 * NB) * sizeof(float);          // ~85.5 KB
  k2_chol<<<16, 64, smem2, stream>>>(ws);
  const size_t smem3 = (size_t)D_TOT * sizeof(float);             // ~105.5 KB
  k3_final<<<1, 256, smem3, stream>>>(x0, v, beta, Cq, ws, out);
}

// Round 3
// 354.824 us; speedup vs baseline: 2.3588x; 2.3588x over previous
//
#include <hip/hip_runtime.h>
#include <math.h>

// Problem constants (reference: N=32, K=16, BINS=100, DIM=2, sample_size=100)
#define NBINS 100
#define NB    101   // BINS+1
#define NN    32
#define KD    16
#define NT    99    // sample_size-1
#define LDM   103   // f64 row stride for M: (2*103)%32=14 -> 16 bank positions (4-way max)

// ws float offsets
#define OFF_S   0        // s[b][j][d] 101*16*2
#define OFF_T   3232     // t[b][j][d]
#define OFF_Q   6464     // Q = C*U 32*16
#define OFF_C   6976     // c_j = sigma^-2 * mu_j (16)
#define OFF_P   6992     // [0]=sigma_sq_inv [1]=-0.5/ls^2
#define OFF_XL  6996     // x_last 64

// ---------------------------------------------------------------- K0: setup
// 256 threads: x_last, G_C -> Jacobi eig (f64, 2 barriers/round, in-place),
// Q = C*U, c_j, params, s-projection.
__global__ __launch_bounds__(256) void k0_setup(
    const float* __restrict__ x0, const float* __restrict__ v,
    const float* __restrict__ sigma_in, const float* __restrict__ ls_in,
    const float* __restrict__ Cq, float* __restrict__ ws)
{
  const int tid = threadIdx.x;
  __shared__ double A[16][17], Vv[16][17];
  __shared__ double csC[8], csS[8];
  __shared__ float CqS[NN * KD];
  __shared__ float Qs[NN * KD];
  __shared__ float xv[NB * 64];

  const float ls = ls_in[0];
  const float inv2ls2 = -0.5f / (ls * ls);
  float sig = fmaxf(sigma_in[0], 0.05f);          // clip(sigma, 5/BINS)
  const float sigma_sq_inv = 1.0f / (sig * sig);

  // x_last = x0 + 0.01 * sum_p v[p]   (64 outputs)
  if (tid < 64) {
    float acc = 0.f;
    for (int p = 0; p < NBINS; ++p) acc += v[p * 64 + tid];
    ws[OFF_XL + tid] = x0[tid] + 0.01f * acc;
  }
  // stage Cq and x0v
  for (int idx = tid; idx < NN * KD; idx += 256) CqS[idx] = Cq[idx];
  for (int idx = tid; idx < NB * 64; idx += 256)
    xv[idx] = (idx < 64) ? x0[idx] : v[idx - 64];
  __syncthreads();

  // G = Cq^T Cq (f64); V = I
  {
    int k1 = tid >> 4, k2 = tid & 15;
    double acc = 0.0;
    for (int n = 0; n < NN; ++n)
      acc += (double)CqS[n * 16 + k1] * (double)CqS[n * 16 + k2];
    A[k1][k2] = acc;
    Vv[k1][k2] = (k1 == k2) ? 1.0 : 0.0;
  }
  __syncthreads();

  // Jacobi: 7 sweeps x 15 rounds x 2 barriers. Rows/cols partitioned by pair;
  // each pair's 16 threads live in one wave -> in-place rotation is race-free.
  for (int sweep = 0; sweep < 7; ++sweep)
  for (int r = 0; r < 15; ++r) {
    const int half = tid >> 7;          // 0: rotate A ; 1: rotate V
    const int it = tid & 127;
    const int i = it >> 4, cr = it & 15;
    int p = (i == 0) ? 0 : (1 + ((i - 1 + r) % 15));
    int q = 1 + ((14 - i + r) % 15);
    if (p > q) { int tt = p; p = q; q = tt; }
    double c = 1.0, s = 0.0;
    if (half == 0) {
      double app = A[p][p], aqq = A[q][q], apq = A[p][q];
      if (fabs(apq) > 1e-300) {
        double th = (aqq - app) / (2.0 * apq);
        double t_ = ((th >= 0.0) ? 1.0 : -1.0) / (fabs(th) + sqrt(th * th + 1.0));
        c = 1.0 / sqrt(t_ * t_ + 1.0);
        s = t_ * c;
      }
      // row rotate (in place; loads precede stores in lockstep wave)
      double ap = A[p][cr], aq = A[q][cr];
      A[p][cr] = c * ap - s * aq;
      A[q][cr] = s * ap + c * aq;
      if (cr == 0) { csC[i] = c; csS[i] = s; }
    }
    __syncthreads();
    if (half == 0) {                    // col rotate with register c,s
      double ap = A[cr][p], aq = A[cr][q];
      A[cr][p] = c * ap - s * aq;
      A[cr][q] = s * ap + c * aq;
    } else {                            // V rotate with LDS c,s
      double cc = csC[i], ss = csS[i];
      double vp = Vv[cr][p], vq = Vv[cr][q];
      Vv[cr][p] = cc * vp - ss * vq;
      Vv[cr][q] = ss * vp + cc * vq;
    }
    __syncthreads();
  }

  if (tid < 16) {
    double mu = A[tid][tid];
    if (mu < 0.0) mu = 0.0;
    ws[OFF_C + tid] = (float)((double)sigma_sq_inv * mu);
  }
  if (tid == 0) { ws[OFF_P + 0] = sigma_sq_inv; ws[OFF_P + 1] = inv2ls2; }

  // Q = C * U
  for (int it = tid; it < NN * KD; it += 256) {
    int n = it >> 4, jq = it & 15;
    double acc = 0.0;
    for (int k2 = 0; k2 < 16; ++k2) acc += (double)CqS[n * 16 + k2] * Vv[k2][jq];
    Qs[it] = (float)acc;
    ws[OFF_Q + it] = (float)acc;
  }
  __syncthreads();

  // s[b][j][d] = sum_n Q[n][j] * x0v[b][n][d]  (lanes contiguous in b)
  for (int it = tid; it < NB * KD; it += 256) {
    int jq = it / NB, b = it - jq * NB;
    float a0 = 0.f, a1 = 0.f;
    for (int n = 0; n < NN; ++n) {
      float qv = Qs[n * 16 + jq];
      a0 += qv * xv[b * 64 + 2 * n];
      a1 += qv * xv[b * 64 + 2 * n + 1];
    }
    ws[OFF_S + (b * 16 + jq) * 2 + 0] = a0;
    ws[OFF_S + (b * 16 + jq) * 2 + 1] = a1;
  }
}

// ------------------------------------------- K2: per-eigenvalue SPD solve
// Block j (16 blocks, 256 threads): build Btil locally, rhs = Btil*s_j,
// M = I + c_j*Btil, blocked Cholesky (W=16): single-wave barrier-free panel
// factorization + all-thread SYRK; then per-wave triangular solves (d=0,1).
__global__ __launch_bounds__(256) void k2_solve(
    const float* __restrict__ x0c_in, const float* __restrict__ ls_in,
    float* __restrict__ ws)
{
  extern __shared__ double sm[];
  double* Ms   = sm;                     // NB * LDM
  double* invd = Ms + NB * LDM;          // NB
  double* rhs  = invd + NB;              // 2 * NB
  float*  sbuf = (float*)(rhs + 2 * NB); // 2 * NB

  const int tid = threadIdx.x;
  const int j = blockIdx.x;
  const double cj = (double)ws[OFF_C + j];
  const float ls = ls_in[0];
  const float i2 = -0.5f / (ls * ls);
  const float x0c = x0c_in[0];

  // build Btil (f32 values, f64 storage) directly in LDS
  for (int idx = tid; idx < NB * NB; idx += 256) {
    int i = idx / NB, c = idx - i * NB;
    float val;
    if (i == 0 || c == 0) {
      val = (i == 0 && c == 0) ? (x0c * x0c + 1e-5f) : 0.0f;
    } else {
      float dd = (float)(c - i) * 0.01f;
      val = expf(dd * dd * i2);
      if (i == c) val += 1e-5f;
    }
    Ms[i * LDM + c] = (double)val;
  }
  for (int idx = tid; idx < 2 * NB; idx += 256) {
    int d = idx / NB, b = idx - d * NB;
    sbuf[idx] = ws[OFF_S + (b * 16 + j) * 2 + d];
  }
  __syncthreads();

  // rhs = Btil * s
  for (int idx = tid; idx < 2 * NB; idx += 256) {
    int d = idx / NB, b = idx - d * NB;
    double acc = 0.0;
    for (int bp = 0; bp < NB; ++bp)
      acc += Ms[b * LDM + bp] * (double)sbuf[d * NB + bp];
    rhs[idx] = acc;
  }
  __syncthreads();

  // M = I + c * Btil
  for (int idx = tid; idx < NB * NB; idx += 256) {
    int i = idx / NB, c = idx - i * NB;
    double v_ = cj * Ms[i * LDM + c];
    if (i == c) v_ += 1.0;
    Ms[i * LDM + c] = v_;
  }
  __syncthreads();

  // Blocked Cholesky, panel width 16
  for (int k0 = 0; k0 < NB; k0 += 16) {
    const int W = (k0 + 16 <= NB) ? 16 : (NB - k0);
    if (tid < 64) {                      // wave 0: barrier-free panel fact
      const int lane = tid;
      for (int kk = 0; kk < W; ++kk) {
        const int k = k0 + kk;
        double dkk = Ms[k * LDM + k];    // broadcast read
        double piv = sqrt(dkk);
        double ip = 1.0 / piv;
        if (lane == 0) { Ms[k * LDM + k] = piv; invd[k] = ip; }
        for (int r = k + 1 + lane; r < NB; r += 64) Ms[r * LDM + k] *= ip;
        __builtin_amdgcn_wave_barrier();
        const int cend = k0 + W;
        for (int r = k + 1 + lane; r < NB; r += 64) {
          double lr = Ms[r * LDM + k];
          for (int c = k + 1; c < cend; ++c)
            Ms[r * LDM + c] -= lr * Ms[c * LDM + k];   // Ms[c][k]: broadcast
        }
        __builtin_amdgcn_wave_barrier();
      }
    }
    __syncthreads();
    // SYRK trailing update (full square keeps symmetry; depth always 16 here)
    const int kT = k0 + W;
    const int m = NB - kT;
    if (m > 0) {
      const int tr = tid >> 4, tc = tid & 15;
      const int nbk = (m + 15) >> 4;
      for (int rb = 0; rb < nbk; ++rb)
      for (int cb = 0; cb < nbk; ++cb) {
        int rr = kT + rb * 16 + tr, cc = kT + cb * 16 + tc;
        if (rr < NB && cc < NB) {
          double acc = Ms[rr * LDM + cc];
          #pragma unroll
          for (int kk = 0; kk < 16; ++kk)
            acc -= Ms[rr * LDM + k0 + kk] * Ms[cc * LDM + k0 + kk];
          Ms[rr * LDM + cc] = acc;
        }
      }
      __syncthreads();
    }
  }

  // Triangular solves: wave 0 -> d=0, wave 1 -> d=1 (barrier-free per wave)
  {
    const int w = tid >> 6, lane = tid & 63;
    if (w < 2) {
      double* rv = rhs + w * NB;
      for (int i = 0; i < NB; ++i) {     // L y = rhs (column reads, 4-way max)
        double y = rv[i] * invd[i];
        if (lane == 0) rv[i] = y;
        for (int r = i + 1 + lane; r < NB; r += 64)
          rv[r] -= Ms[r * LDM + i] * y;
        __builtin_amdgcn_wave_barrier();
      }
      for (int i = NB - 1; i >= 0; --i) { // L^T t = y (row reads, contiguous)
        double t_ = rv[i] * invd[i];
        if (lane == 0) rv[i] = t_;
        for (int r = lane; r < i; r += 64)
          rv[r] -= Ms[i * LDM + r] * t_;
        __builtin_amdgcn_wave_barrier();
      }
    }
  }
  __syncthreads();

  for (int idx = tid; idx < 2 * NB; idx += 256) {
    int d = idx / NB, b = idx - d * NB;
    ws[OFF_T + (b * 16 + j) * 2 + d] = (float)rhs[d * NB + b];
  }
}

// ---------------- K3 (fused): y, Y2, Bc table, xt, intensity integral
#define D_Q   0
#define D_C   512
#define D_T   1024     // t (3232) -> reused as av
#define D_Y   4256     // y (6464) -> overwritten by Y2
#define D_BC  10720    // Bc 99*100
#define D_XT  20620    // xt 99*64
#define D_XL  26956    // x_last 64
#define D_TOT 27020

__global__ __launch_bounds__(256) void k3_final(
    const float* __restrict__ x0, const float* __restrict__ v,
    const float* __restrict__ beta, const float* __restrict__ Cq,
    const float* __restrict__ ws, float* __restrict__ out)
{
  extern __shared__ float lds[];
  const int tid = threadIdx.x;
  const float sinv    = ws[OFF_P + 0];
  const float inv2ls2 = ws[OFF_P + 1];

  for (int i = tid; i < 512; i += 256) { lds[D_Q + i] = ws[OFF_Q + i]; lds[D_C + i] = Cq[i]; }
  for (int i = tid; i < 3232; i += 256) lds[D_T + i] = ws[OFF_T + i];
  if (tid < 64) lds[D_XL + tid] = ws[OFF_XL + tid];
  __syncthreads();

  // y = sinv*x - sinv^2 * Q t
  for (int idx = tid; idx < NB * 64; idx += 256) {
    int b = idx >> 6, rr = idx & 63, n = rr >> 1, d = rr & 1;
    float acc = 0.f;
    for (int jq = 0; jq < 16; ++jq)
      acc += lds[D_Q + n * 16 + jq] * lds[D_T + b * 32 + jq * 2 + d];
    float xval = (idx < 64) ? x0[idx] : v[idx - 64];
    lds[D_Y + idx] = sinv * xval - sinv * sinv * acc;
  }
  __syncthreads();

  // av = C^T y (into D_T) ; Bc table
  for (int idx = tid; idx < NB * 32; idx += 256) {
    int b = idx >> 5, rr = idx & 31, k = rr >> 1, d = rr & 1;
    float acc = 0.f;
    for (int n = 0; n < NN; ++n)
      acc += lds[D_C + n * 16 + k] * lds[D_Y + b * 64 + n * 2 + d];
    lds[D_T + idx] = acc;
  }
  for (int idx = tid; idx < NT * NBINS; idx += 256) {
    int t = idx / NBINS, p = idx - (idx / NBINS) * NBINS;
    float tst = 1.0f + (float)t * (1.0f / 99.0f);
    float dd = tst - ((float)p + 0.5f) * 0.01f;
    lds[D_BC + idx] = expf(dd * dd * inv2ls2);
  }
  __syncthreads();

  // Y2 = C av (overwrite D_Y)
  for (int idx = tid; idx < NB * 64; idx += 256) {
    int b = idx >> 6, rr = idx & 63, n = rr >> 1, d = rr & 1;
    float acc = 0.f;
    for (int k = 0; k < 16; ++k)
      acc += lds[D_C + n * 16 + k] * lds[D_T + b * 32 + k * 2 + d];
    lds[D_Y + idx] = acc;
  }
  __syncthreads();

  // xt[t][n][:] = x_last + trel * sum_p Bc[t][p] * Y2[p+1][n][:]
  {
    const int n = tid & 31, tg = tid >> 5;
    float ax[13], ay[13];
    for (int s = 0; s < 13; ++s) { ax[s] = 0.f; ay[s] = 0.f; }
    for (int p = 0; p < NBINS; ++p) {
      float2 yv = *(const float2*)&lds[D_Y + (p + 1) * 64 + 2 * n];
      #pragma unroll
      for (int s = 0; s < 13; ++s) {
        int t = tg * 13 + s;
        if (t < NT) {
          float bc = lds[D_BC + t * NBINS + p];
          ax[s] += bc * yv.x;
          ay[s] += bc * yv.y;
        }
      }
    }
    float xlx = lds[D_XL + 2 * n], xly = lds[D_XL + 2 * n + 1];
    for (int s = 0; s < 13; ++s) {
      int t = tg * 13 + s;
      if (t < NT) {
        float trel = (float)t * (1.0f / 99.0f);
        lds[D_XT + t * 64 + 2 * n]     = xlx + trel * ax[s];
        lds[D_XT + t * 64 + 2 * n + 1] = xly + trel * ay[s];
      }
    }
  }
  __syncthreads();

  // intensity integral
  for (int pair = tid; pair < NN * NN; pair += 256) {
    int i = pair >> 5, jj = pair & 31;
    float bsum = beta[i] + beta[jj];
    float acc = 0.f;
    for (int t = 0; t < NT; ++t) {
      float2 xi = *(const float2*)&lds[D_XT + t * 64 + 2 * i];
      float2 xj = *(const float2*)&lds[D_XT + t * 64 + 2 * jj];
      float dx = xi.x - xj.x, dy = xi.y - xj.y;
      float sq = fmaxf(dx * dx + dy * dy, 1e-12f);
      acc += expf(bsum - sqrtf(sq));
    }
    out[pair] = acc * (1.0f / 99.0f);
  }
}

extern "C" void kernel_launch(void* const* d_in, const int* in_sizes, int n_in,
                              void* d_out, int out_size, void* d_ws, size_t ws_size,
                              hipStream_t stream) {
  const float* x0    = (const float*)d_in[0];
  const float* v     = (const float*)d_in[1];
  const float* beta  = (const float*)d_in[2];
  const float* sigma = (const float*)d_in[3];
  const float* x0c   = (const float*)d_in[4];
  const float* ls    = (const float*)d_in[5];
  const float* Cq    = (const float*)d_in[6];
  float* out = (float*)d_out;
  float* ws  = (float*)d_ws;

  k0_setup<<<1, 256, 0, stream>>>(x0, v, sigma, ls, Cq, ws);
  const size_t smem2 = (size_t)(NB * LDM + NB + 2 * NB) * sizeof(double)
                     + (size_t)(2 * NB) * sizeof(float);           // ~86.5 KB
  k2_solve<<<16, 256, smem2, stream>>>(x0c, ls, ws);
  const size_t smem3 = (size_t)D_TOT * sizeof(float);              // ~105.5 KB
  k3_final<<<1, 256, smem3, stream>>>(x0, v, beta, Cq, ws, out);
}

// Round 4
// 270.682 us; speedup vs baseline: 3.0920x; 1.3109x over previous
//
#include <hip/hip_runtime.h>
#include <math.h>

// Problem constants (reference: N=32, K=16, BINS=100, DIM=2, sample_size=100)
#define NBINS 100
#define NB    101   // BINS+1
#define NN    32
#define KD    16
#define NT    99    // sample_size-1

// ws float offsets
#define OFF_S   0        // s[b][j][d] 101*16*2
#define OFF_T   3232     // t[b][j][d]
#define OFF_Q   6464     // Q = C*U 32*16
#define OFF_C   6976     // c_j = sigma^-2 * mu_j (16)
#define OFF_P   6992     // [0]=sigma_sq_inv [1]=-0.5/ls^2
#define OFF_XL  6996     // x_last 64

// ---------------------------------------------------------------- K0: setup
// 256 threads: x_last, G_C -> Jacobi eig (f64, 2 barriers/round, in-place),
// Q = C*U, c_j, params, s-projection.
__global__ __launch_bounds__(256) void k0_setup(
    const float* __restrict__ x0, const float* __restrict__ v,
    const float* __restrict__ sigma_in, const float* __restrict__ ls_in,
    const float* __restrict__ Cq, float* __restrict__ ws)
{
  const int tid = threadIdx.x;
  __shared__ double A[16][17], Vv[16][17];
  __shared__ double csC[8], csS[8];
  __shared__ float CqS[NN * KD];
  __shared__ float Qs[NN * KD];
  __shared__ float xv[NB * 64];

  const float ls = ls_in[0];
  const float inv2ls2 = -0.5f / (ls * ls);
  float sig = fmaxf(sigma_in[0], 0.05f);          // clip(sigma, 5/BINS)
  const float sigma_sq_inv = 1.0f / (sig * sig);

  // x_last = x0 + 0.01 * sum_p v[p]   (64 outputs)
  if (tid < 64) {
    float acc = 0.f;
    for (int p = 0; p < NBINS; ++p) acc += v[p * 64 + tid];
    ws[OFF_XL + tid] = x0[tid] + 0.01f * acc;
  }
  // stage Cq and x0v
  for (int idx = tid; idx < NN * KD; idx += 256) CqS[idx] = Cq[idx];
  for (int idx = tid; idx < NB * 64; idx += 256)
    xv[idx] = (idx < 64) ? x0[idx] : v[idx - 64];
  __syncthreads();

  // G = Cq^T Cq (f64); V = I
  {
    int k1 = tid >> 4, k2 = tid & 15;
    double acc = 0.0;
    for (int n = 0; n < NN; ++n)
      acc += (double)CqS[n * 16 + k1] * (double)CqS[n * 16 + k2];
    A[k1][k2] = acc;
    Vv[k1][k2] = (k1 == k2) ? 1.0 : 0.0;
  }
  __syncthreads();

  // Jacobi: 6 sweeps x 15 rounds x 2 barriers.
  for (int sweep = 0; sweep < 6; ++sweep)
  for (int r = 0; r < 15; ++r) {
    const int half = tid >> 7;          // 0: rotate A ; 1: rotate V
    const int it = tid & 127;
    const int i = it >> 4, cr = it & 15;
    int p = (i == 0) ? 0 : (1 + ((i - 1 + r) % 15));
    int q = 1 + ((14 - i + r) % 15);
    if (p > q) { int tt = p; p = q; q = tt; }
    double c = 1.0, s = 0.0;
    if (half == 0) {
      double app = A[p][p], aqq = A[q][q], apq = A[p][q];
      if (fabs(apq) > 1e-300) {
        double th = (aqq - app) / (2.0 * apq);
        double t_ = ((th >= 0.0) ? 1.0 : -1.0) / (fabs(th) + sqrt(th * th + 1.0));
        c = 1.0 / sqrt(t_ * t_ + 1.0);
        s = t_ * c;
      }
      double ap = A[p][cr], aq = A[q][cr];
      A[p][cr] = c * ap - s * aq;
      A[q][cr] = s * ap + c * aq;
      if (cr == 0) { csC[i] = c; csS[i] = s; }
    }
    __syncthreads();
    if (half == 0) {
      double ap = A[cr][p], aq = A[cr][q];
      A[cr][p] = c * ap - s * aq;
      A[cr][q] = s * ap + c * aq;
    } else {
      double cc = csC[i], ss = csS[i];
      double vp = Vv[cr][p], vq = Vv[cr][q];
      Vv[cr][p] = cc * vp - ss * vq;
      Vv[cr][q] = ss * vp + cc * vq;
    }
    __syncthreads();
  }

  if (tid < 16) {
    double mu = A[tid][tid];
    if (mu < 0.0) mu = 0.0;
    ws[OFF_C + tid] = (float)((double)sigma_sq_inv * mu);
  }
  if (tid == 0) { ws[OFF_P + 0] = sigma_sq_inv; ws[OFF_P + 1] = inv2ls2; }

  // Q = C * U
  for (int it = tid; it < NN * KD; it += 256) {
    int n = it >> 4, jq = it & 15;
    double acc = 0.0;
    for (int k2 = 0; k2 < 16; ++k2) acc += (double)CqS[n * 16 + k2] * Vv[k2][jq];
    Qs[it] = (float)acc;
    ws[OFF_Q + it] = (float)acc;
  }
  __syncthreads();

  // s[b][j][d] = sum_n Q[n][j] * x0v[b][n][d]
  for (int it = tid; it < NB * KD; it += 256) {
    int jq = it / NB, b = it - jq * NB;
    float a0 = 0.f, a1 = 0.f;
    for (int n = 0; n < NN; ++n) {
      float qv = Qs[n * 16 + jq];
      a0 += qv * xv[b * 64 + 2 * n];
      a1 += qv * xv[b * 64 + 2 * n + 1];
    }
    ws[OFF_S + (b * 16 + jq) * 2 + 0] = a0;
    ws[OFF_S + (b * 16 + jq) * 2 + 1] = a1;
  }
}

// ------------------------------------------- K2: Toeplitz Levinson solve
// B~ = blockdiag(x0c^2+eps, T) with T symmetric Toeplitz (uniform centers).
// System j: (I + c_j B~) t = B~ s  ->  scalar top solve + Levinson on
// (I + c_j T) x = T s_tail, 2 RHS, n=100.  One wave per block; whole
// recursion in registers (2 elems/lane); reversed vectors maintained by
// shfl_up shifts; 3 fused butterfly reductions per step. f64.
__global__ __launch_bounds__(64) void k2_toep(
    const float* __restrict__ x0c_in, const float* __restrict__ ls_in,
    float* __restrict__ ws)
{
  __shared__ float gs[100];
  __shared__ float ss[2][100];
  const int l = threadIdx.x;
  const int j = blockIdx.x;
  const double c = (double)ws[OFF_C + j];
  const float ls = ls_in[0];
  const float i2 = -0.5f / (ls * ls);
  const int ahi = 64 + l;                       // hi-slot element index

  for (int k = l; k < 100; k += 64) {
    float dd = 0.01f * (float)k;
    gs[k] = expf(dd * dd * i2);
  }
  for (int idx = l; idx < 200; idx += 64) {
    int d = idx / 100, b = idx - d * 100;
    ss[d][b] = ws[OFF_S + ((b + 1) * 16 + j) * 2 + d];
  }
  __syncthreads();

  const double m0  = 1.0 + c * (1.0 + 1e-5);
  const double im0 = 1.0 / m0;

  // rho[k] = c*g[k]/m0 (k>=1), rho[0]=1
  double rho_lo = (l == 0) ? 1.0 : c * (double)gs[l] * im0;
  double rho_hi = (l < 36) ? c * (double)gs[64 + l] * im0 : 0.0;

  // rhs = T*s (rows l and 64+l), then bhat = rhs/m0
  double r0_lo = 0, r1_lo = 0, r0_hi = 0, r1_hi = 0;
  for (int b = 0; b < 100; ++b) {
    float s0 = ss[0][b], s1 = ss[1][b];
    int dlo = l - b; dlo = dlo < 0 ? -dlo : dlo;
    float glo = gs[dlo];
    r0_lo += (double)glo * (double)s0;
    r1_lo += (double)glo * (double)s1;
    if (ahi < 100) {
      int dhi = ahi - b;
      float ghi = gs[dhi < 0 ? -dhi : dhi];
      r0_hi += (double)ghi * (double)s0;
      r1_hi += (double)ghi * (double)s1;
    }
  }
  double b0_lo = (r0_lo + 1e-5 * (double)ss[0][l]) * im0;
  double b1_lo = (r1_lo + 1e-5 * (double)ss[1][l]) * im0;
  double b0_hi = 0.0, b1_hi = 0.0;
  if (ahi < 100) {
    b0_hi = (r0_hi + 1e-5 * (double)ss[0][ahi]) * im0;
    b1_hi = (r1_hi + 1e-5 * (double)ss[1][ahi]) * im0;
  }

  // Levinson init (element 0)
  double rho1 = __shfl(rho_lo, 1, 64);
  double bb00 = __shfl(b0_lo, 0, 64);
  double bb10 = __shfl(b1_lo, 0, 64);
  double x0_lo = (l == 0) ? bb00 : 0.0, x0_hi = 0.0;
  double x1_lo = (l == 0) ? bb10 : 0.0, x1_hi = 0.0;
  double y_lo  = (l == 0) ? -rho1 : 0.0, y_hi = 0.0;
  double yr_lo = (l == 0) ? -rho1 : 0.0, yr_hi = 0.0;  // y reversed (len k)
  double rr_lo = (l == 0) ?  rho1 : 0.0, rr_hi = 0.0;  // rho[k-i]
  double alpha = -rho1, beta = 1.0;

  for (int k = 1; k < 100; ++k) {
    beta *= (1.0 - alpha * alpha);
    double ib = 1.0 / beta;
    const bool lo_on = (l < k);
    const bool hi_on = (ahi < k);
    double px0 = (lo_on ? rr_lo * x0_lo : 0.0) + (hi_on ? rr_hi * x0_hi : 0.0);
    double px1 = (lo_on ? rr_lo * x1_lo : 0.0) + (hi_on ? rr_hi * x1_hi : 0.0);
    double py  = (lo_on ? rr_lo * y_lo  : 0.0) + (hi_on ? rr_hi * y_hi  : 0.0);
    #pragma unroll
    for (int m = 1; m < 64; m <<= 1) {
      px0 += __shfl_xor(px0, m, 64);
      px1 += __shfl_xor(px1, m, 64);
      py  += __shfl_xor(py , m, 64);
    }
    double bk0 = (k < 64) ? __shfl(b0_lo, k, 64) : __shfl(b0_hi, k - 64, 64);
    double bk1 = (k < 64) ? __shfl(b1_lo, k, 64) : __shfl(b1_hi, k - 64, 64);
    double rk1 = 0.0;
    if (k < 99)
      rk1 = (k + 1 < 64) ? __shfl(rho_lo, k + 1, 64) : __shfl(rho_hi, k - 63, 64);
    double mu0 = (bk0 - px0) * ib;
    double mu1 = (bk1 - px1) * ib;
    double an  = -(rk1 + py) * ib;
    // w = yrev_old + an*y_old  (pre-update) -> next yrev via shift
    double w_lo = yr_lo + an * y_lo;
    double w_hi = yr_hi + an * y_hi;
    if (lo_on) { x0_lo += mu0 * yr_lo; x1_lo += mu1 * yr_lo; y_lo += an * yr_lo; }
    if (hi_on) { x0_hi += mu0 * yr_hi; x1_hi += mu1 * yr_hi; y_hi += an * yr_hi; }
    if (k < 64) { if (l == k)      { x0_lo = mu0; x1_lo = mu1; y_lo = an; } }
    else        { if (l == k - 64) { x0_hi = mu0; x1_hi = mu1; y_hi = an; } }
    double su_lo = __shfl_up(w_lo, 1, 64);
    double su_hi = __shfl_up(w_hi, 1, 64);
    double w63   = __shfl(w_lo, 63, 64);
    yr_lo = (l == 0) ? an  : su_lo;
    yr_hi = (l == 0) ? w63 : su_hi;
    double ru_lo = __shfl_up(rr_lo, 1, 64);
    double ru_hi = __shfl_up(rr_hi, 1, 64);
    double r63   = __shfl(rr_lo, 63, 64);
    rr_lo = (l == 0) ? rk1 : ru_lo;
    rr_hi = (l == 0) ? r63 : ru_hi;
    alpha = an;
  }

  // outputs
  if (l == 0) {
    const float x0c = x0c_in[0];
    double b00 = (double)(x0c * x0c) + 1e-5;
    double s0 = (double)ws[OFF_S + j * 2 + 0];
    double s1 = (double)ws[OFF_S + j * 2 + 1];
    double den = 1.0 / (1.0 + c * b00);
    ws[OFF_T + j * 2 + 0] = (float)(b00 * s0 * den);
    ws[OFF_T + j * 2 + 1] = (float)(b00 * s1 * den);
  }
  ws[OFF_T + ((l + 1) * 16 + j) * 2 + 0] = (float)x0_lo;
  ws[OFF_T + ((l + 1) * 16 + j) * 2 + 1] = (float)x1_lo;
  if (ahi < 100) {
    ws[OFF_T + ((ahi + 1) * 16 + j) * 2 + 0] = (float)x0_hi;
    ws[OFF_T + ((ahi + 1) * 16 + j) * 2 + 1] = (float)x1_hi;
  }
}

// ---------------- K3 (fused): y, Y2, Bc table, xt, intensity integral
#define D_Q   0
#define D_C   512
#define D_T   1024     // t (3232) -> reused as av
#define D_Y   4256     // y (6464) -> overwritten by Y2
#define D_BC  10720    // Bc 99*100
#define D_XT  20620    // xt 99*64
#define D_XL  26956    // x_last 64
#define D_TOT 27020

__global__ __launch_bounds__(256) void k3_final(
    const float* __restrict__ x0, const float* __restrict__ v,
    const float* __restrict__ beta, const float* __restrict__ Cq,
    const float* __restrict__ ws, float* __restrict__ out)
{
  extern __shared__ float lds[];
  const int tid = threadIdx.x;
  const float sinv    = ws[OFF_P + 0];
  const float inv2ls2 = ws[OFF_P + 1];

  for (int i = tid; i < 512; i += 256) { lds[D_Q + i] = ws[OFF_Q + i]; lds[D_C + i] = Cq[i]; }
  for (int i = tid; i < 3232; i += 256) lds[D_T + i] = ws[OFF_T + i];
  if (tid < 64) lds[D_XL + tid] = ws[OFF_XL + tid];
  __syncthreads();

  // y = sinv*x - sinv^2 * Q t
  for (int idx = tid; idx < NB * 64; idx += 256) {
    int b = idx >> 6, rr = idx & 63, n = rr >> 1, d = rr & 1;
    float acc = 0.f;
    for (int jq = 0; jq < 16; ++jq)
      acc += lds[D_Q + n * 16 + jq] * lds[D_T + b * 32 + jq * 2 + d];
    float xval = (idx < 64) ? x0[idx] : v[idx - 64];
    lds[D_Y + idx] = sinv * xval - sinv * sinv * acc;
  }
  __syncthreads();

  // av = C^T y (into D_T) ; Bc table
  for (int idx = tid; idx < NB * 32; idx += 256) {
    int b = idx >> 5, rr = idx & 31, k = rr >> 1, d = rr & 1;
    float acc = 0.f;
    for (int n = 0; n < NN; ++n)
      acc += lds[D_C + n * 16 + k] * lds[D_Y + b * 64 + n * 2 + d];
    lds[D_T + idx] = acc;
  }
  for (int idx = tid; idx < NT * NBINS; idx += 256) {
    int t = idx / NBINS, p = idx - (idx / NBINS) * NBINS;
    float tst = 1.0f + (float)t * (1.0f / 99.0f);
    float dd = tst - ((float)p + 0.5f) * 0.01f;
    lds[D_BC + idx] = expf(dd * dd * inv2ls2);
  }
  __syncthreads();

  // Y2 = C av (overwrite D_Y)
  for (int idx = tid; idx < NB * 64; idx += 256) {
    int b = idx >> 6, rr = idx & 63, n = rr >> 1, d = rr & 1;
    float acc = 0.f;
    for (int k = 0; k < 16; ++k)
      acc += lds[D_C + n * 16 + k] * lds[D_T + b * 32 + k * 2 + d];
    lds[D_Y + idx] = acc;
  }
  __syncthreads();

  // xt[t][n][:] = x_last + trel * sum_p Bc[t][p] * Y2[p+1][n][:]
  {
    const int n = tid & 31, tg = tid >> 5;
    float ax[13], ay[13];
    for (int s = 0; s < 13; ++s) { ax[s] = 0.f; ay[s] = 0.f; }
    for (int p = 0; p < NBINS; ++p) {
      float2 yv = *(const float2*)&lds[D_Y + (p + 1) * 64 + 2 * n];
      #pragma unroll
      for (int s = 0; s < 13; ++s) {
        int t = tg * 13 + s;
        if (t < NT) {
          float bc = lds[D_BC + t * NBINS + p];
          ax[s] += bc * yv.x;
          ay[s] += bc * yv.y;
        }
      }
    }
    float xlx = lds[D_XL + 2 * n], xly = lds[D_XL + 2 * n + 1];
    for (int s = 0; s < 13; ++s) {
      int t = tg * 13 + s;
      if (t < NT) {
        float trel = (float)t * (1.0f / 99.0f);
        lds[D_XT + t * 64 + 2 * n]     = xlx + trel * ax[s];
        lds[D_XT + t * 64 + 2 * n + 1] = xly + trel * ay[s];
      }
    }
  }
  __syncthreads();

  // intensity integral
  for (int pair = tid; pair < NN * NN; pair += 256) {
    int i = pair >> 5, jj = pair & 31;
    float bsum = beta[i] + beta[jj];
    float acc = 0.f;
    for (int t = 0; t < NT; ++t) {
      float2 xi = *(const float2*)&lds[D_XT + t * 64 + 2 * i];
      float2 xj = *(const float2*)&lds[D_XT + t * 64 + 2 * jj];
      float dx = xi.x - xj.x, dy = xi.y - xj.y;
      float sq = fmaxf(dx * dx + dy * dy, 1e-12f);
      acc += expf(bsum - sqrtf(sq));
    }
    out[pair] = acc * (1.0f / 99.0f);
  }
}

extern "C" void kernel_launch(void* const* d_in, const int* in_sizes, int n_in,
                              void* d_out, int out_size, void* d_ws, size_t ws_size,
                              hipStream_t stream) {
  const float* x0    = (const float*)d_in[0];
  const float* v     = (const float*)d_in[1];
  const float* beta  = (const float*)d_in[2];
  const float* sigma = (const float*)d_in[3];
  const float* x0c   = (const float*)d_in[4];
  const float* ls    = (const float*)d_in[5];
  const float* Cq    = (const float*)d_in[6];
  float* out = (float*)d_out;
  float* ws  = (float*)d_ws;

  k0_setup<<<1, 256, 0, stream>>>(x0, v, sigma, ls, Cq, ws);
  k2_toep<<<16, 64, 0, stream>>>(x0c, ls, ws);
  const size_t smem3 = (size_t)D_TOT * sizeof(float);              // ~105.5 KB
  k3_final<<<1, 256, smem3, stream>>>(x0, v, beta, Cq, ws, out);
}

// Round 5
// 238.454 us; speedup vs baseline: 3.5099x; 1.1352x over previous
//
#include <hip/hip_runtime.h>
#include <math.h>

// Problem constants (reference: N=32, K=16, BINS=100, DIM=2, sample_size=100)
#define NBINS 100
#define NN    32
#define KD    16
#define NT    99    // sample_size-1

// ws float offsets
#define OFF_H   0        // h[p][j][d] 100*16*2 = 3200
#define OFF_QT  3200     // qt[j][n] = Q[n][j]  16*32 = 512
#define OFF_XL  3712     // x_last 64

// =============================== K2: everything up to h ====================
// 16 blocks (one per eigen-system j), 64 threads = 1 wave.
// Each block redundantly: stage v^T + Cq, G = C^T C, Jacobi eig (f64, in-wave),
// c_j, Q, s_j projection, rhs = T*s, Levinson (2 RHS, registers+shuffles),
// h_j = sinv*(s_j - c_j * x). Block 0 additionally writes Q^T and x_last.
__global__ __launch_bounds__(64) void k2_all(
    const float* __restrict__ x0, const float* __restrict__ v,
    const float* __restrict__ sigma_in, const float* __restrict__ ls_in,
    const float* __restrict__ Cq, float* __restrict__ ws)
{
  __shared__ float  vT[64 * 101];          // vT[nd][p], stride 101 (conflict-free)
  __shared__ float  CqS[NN * KD];
  __shared__ double A[16][17], Vv[16][17];
  __shared__ double csC[8], csS[8];
  __shared__ float  Qs[NN * KD];           // Q[n][j] at n*16+j
  __shared__ float  gs[100];
  __shared__ float  ss[200];               // ss[d*100+p]

  const int l = threadIdx.x;
  const int j = blockIdx.x;
  const float ls = ls_in[0];
  const float i2 = -0.5f / (ls * ls);
  float sig = fmaxf(sigma_in[0], 0.05f);   // clip(sigma, 5/BINS)
  const double sinvd = 1.0 / ((double)sig * (double)sig);
  const float sinv = (float)sinvd;

  // ---- stage: vT (transposed, padded), Cq, gs ----
  for (int p = 0; p < NBINS; ++p) vT[l * 101 + p] = v[p * 64 + l];
  for (int e = l; e < NN * KD; e += 64) CqS[e] = Cq[e];
  for (int k = l; k < 100; k += 64) {
    float dd = 0.01f * (float)k;
    gs[k] = expf(dd * dd * i2);
  }
  __syncthreads();

  if (j == 0) {                            // x_last (block 0 only)
    float acc = 0.f;
    for (int p = 0; p < NBINS; ++p) acc += vT[l * 101 + p];
    ws[OFF_XL + l] = x0[l] + 0.01f * acc;
  }

  // ---- G = Cq^T Cq (f64), V = I ----
  for (int e = l; e < 256; e += 64) {
    int k1 = e >> 4, k2 = e & 15;
    double acc = 0.0;
    for (int n = 0; n < NN; ++n)
      acc += (double)CqS[n * 16 + k1] * (double)CqS[n * 16 + k2];
    A[k1][k2] = acc;
    Vv[k1][k2] = (k1 == k2) ? 1.0 : 0.0;
  }
  __syncthreads();

  // ---- Jacobi: 6 sweeps x 15 rounds, single-wave (cheap fences) ----
  for (int sweep = 0; sweep < 6; ++sweep)
  for (int r = 0; r < 15; ++r) {
    if (l < 8) {
      int i = l;
      int p = (i == 0) ? 0 : (1 + ((i - 1 + r) % 15));
      int q = 1 + ((14 - i + r) % 15);
      if (p > q) { int tt = p; p = q; q = tt; }
      double app = A[p][p], aqq = A[q][q], apq = A[p][q];
      double c = 1.0, s = 0.0;
      if (fabs(apq) > 1e-300) {
        double th = (aqq - app) / (2.0 * apq);
        double t_ = ((th >= 0.0) ? 1.0 : -1.0) / (fabs(th) + sqrt(th * th + 1.0));
        c = 1.0 / sqrt(t_ * t_ + 1.0);
        s = t_ * c;
      }
      csC[i] = c; csS[i] = s;
    }
    __syncthreads();
    // row rotate: 128 (i,col) combos, 2 per lane
    for (int e = l; e < 128; e += 64) {
      int i = e >> 4, col = e & 15;
      int p = (i == 0) ? 0 : (1 + ((i - 1 + r) % 15));
      int q = 1 + ((14 - i + r) % 15);
      if (p > q) { int tt = p; p = q; q = tt; }
      double c = csC[i], s = csS[i];
      double ap = A[p][col], aq = A[q][col];
      A[p][col] = c * ap - s * aq;
      A[q][col] = s * ap + c * aq;
    }
    __syncthreads();
    // col rotate (A) + V rotate: 256 combos, 4 per lane
    for (int e = l; e < 256; e += 64) {
      int t2 = e & 127;
      int i = t2 >> 4, row = t2 & 15;
      int p = (i == 0) ? 0 : (1 + ((i - 1 + r) % 15));
      int q = 1 + ((14 - i + r) % 15);
      if (p > q) { int tt = p; p = q; q = tt; }
      double c = csC[i], s = csS[i];
      if (e < 128) {
        double ap = A[row][p], aq = A[row][q];
        A[row][p] = c * ap - s * aq;
        A[row][q] = s * ap + c * aq;
      } else {
        double vp = Vv[row][p], vq = Vv[row][q];
        Vv[row][p] = c * vp - s * vq;
        Vv[row][q] = s * vp + c * vq;
      }
    }
    __syncthreads();
  }

  // c_j for this block (broadcast read)
  double muj = A[j][j];
  if (muj < 0.0) muj = 0.0;
  const double c = sinvd * muj;

  // ---- Q = C * U ----
  for (int e = l; e < NN * KD; e += 64) {
    int n = e >> 4, jq = e & 15;
    double acc = 0.0;
    for (int k2 = 0; k2 < 16; ++k2) acc += (double)CqS[n * 16 + k2] * Vv[k2][jq];
    Qs[e] = (float)acc;
  }
  __syncthreads();

  if (j == 0) {                            // Q^T to ws (block 0 only)
    for (int e = l; e < NN * KD; e += 64) {
      int jq = e >> 5, n = e & 31;
      ws[OFF_QT + e] = Qs[n * 16 + jq];
    }
  }

  // ---- s_j[d][p] = sum_n Q[n][j] * v[p][n][d]  (conflict-free vT reads) ----
  for (int e = l; e < 200; e += 64) {
    int d = e / 100, p = e - d * 100;
    float acc = 0.f;
    for (int n = 0; n < NN; ++n)
      acc += Qs[n * 16 + j] * vT[(2 * n + d) * 101 + p];
    ss[e] = acc;
  }
  __syncthreads();

  // ---- Levinson on (I + c*T) x = T*s, 2 RHS, n=100 (registers/shuffles) ----
  const int ahi = 64 + l;
  const double m0  = 1.0 + c * (1.0 + 1e-5);
  const double im0 = 1.0 / m0;

  double rho_lo = (l == 0) ? 1.0 : c * (double)gs[l] * im0;
  double rho_hi = (l < 36) ? c * (double)gs[64 + l] * im0 : 0.0;

  double r0_lo = 0, r1_lo = 0, r0_hi = 0, r1_hi = 0;
  for (int b = 0; b < 100; ++b) {
    float s0 = ss[b], s1 = ss[100 + b];
    int dlo = l - b; dlo = dlo < 0 ? -dlo : dlo;
    float glo = gs[dlo];
    r0_lo += (double)glo * (double)s0;
    r1_lo += (double)glo * (double)s1;
    if (ahi < 100) {
      int dhi = ahi - b;
      float ghi = gs[dhi < 0 ? -dhi : dhi];
      r0_hi += (double)ghi * (double)s0;
      r1_hi += (double)ghi * (double)s1;
    }
  }
  double b0_lo = (r0_lo + 1e-5 * (double)ss[l])       * im0;
  double b1_lo = (r1_lo + 1e-5 * (double)ss[100 + l]) * im0;
  double b0_hi = 0.0, b1_hi = 0.0;
  if (ahi < 100) {
    b0_hi = (r0_hi + 1e-5 * (double)ss[ahi])       * im0;
    b1_hi = (r1_hi + 1e-5 * (double)ss[100 + ahi]) * im0;
  }

  double rho1 = __shfl(rho_lo, 1, 64);
  double bb00 = __shfl(b0_lo, 0, 64);
  double bb10 = __shfl(b1_lo, 0, 64);
  double x0_lo = (l == 0) ? bb00 : 0.0, x0_hi = 0.0;
  double x1_lo = (l == 0) ? bb10 : 0.0, x1_hi = 0.0;
  double y_lo  = (l == 0) ? -rho1 : 0.0, y_hi = 0.0;
  double yr_lo = (l == 0) ? -rho1 : 0.0, yr_hi = 0.0;
  double rr_lo = (l == 0) ?  rho1 : 0.0, rr_hi = 0.0;
  double alpha = -rho1, beta = 1.0;

  for (int k = 1; k < 100; ++k) {
    beta *= (1.0 - alpha * alpha);
    double ib = 1.0 / beta;
    const bool lo_on = (l < k);
    const bool hi_on = (ahi < k);
    double px0 = (lo_on ? rr_lo * x0_lo : 0.0) + (hi_on ? rr_hi * x0_hi : 0.0);
    double px1 = (lo_on ? rr_lo * x1_lo : 0.0) + (hi_on ? rr_hi * x1_hi : 0.0);
    double py  = (lo_on ? rr_lo * y_lo  : 0.0) + (hi_on ? rr_hi * y_hi  : 0.0);
    #pragma unroll
    for (int m = 1; m < 64; m <<= 1) {
      px0 += __shfl_xor(px0, m, 64);
      px1 += __shfl_xor(px1, m, 64);
      py  += __shfl_xor(py , m, 64);
    }
    double bk0 = (k < 64) ? __shfl(b0_lo, k, 64) : __shfl(b0_hi, k - 64, 64);
    double bk1 = (k < 64) ? __shfl(b1_lo, k, 64) : __shfl(b1_hi, k - 64, 64);
    double rk1 = 0.0;
    if (k < 99)
      rk1 = (k + 1 < 64) ? __shfl(rho_lo, k + 1, 64) : __shfl(rho_hi, k - 63, 64);
    double mu0 = (bk0 - px0) * ib;
    double mu1 = (bk1 - px1) * ib;
    double an  = -(rk1 + py) * ib;
    double w_lo = yr_lo + an * y_lo;
    double w_hi = yr_hi + an * y_hi;
    if (lo_on) { x0_lo += mu0 * yr_lo; x1_lo += mu1 * yr_lo; y_lo += an * yr_lo; }
    if (hi_on) { x0_hi += mu0 * yr_hi; x1_hi += mu1 * yr_hi; y_hi += an * yr_hi; }
    if (k < 64) { if (l == k)      { x0_lo = mu0; x1_lo = mu1; y_lo = an; } }
    else        { if (l == k - 64) { x0_hi = mu0; x1_hi = mu1; y_hi = an; } }
    double su_lo = __shfl_up(w_lo, 1, 64);
    double su_hi = __shfl_up(w_hi, 1, 64);
    double w63   = __shfl(w_lo, 63, 64);
    yr_lo = (l == 0) ? an  : su_lo;
    yr_hi = (l == 0) ? w63 : su_hi;
    double ru_lo = __shfl_up(rr_lo, 1, 64);
    double ru_hi = __shfl_up(rr_hi, 1, 64);
    double r63   = __shfl(rr_lo, 63, 64);
    rr_lo = (l == 0) ? rk1 : ru_lo;
    rr_hi = (l == 0) ? r63 : ru_hi;
    alpha = an;
  }

  // ---- h[p][j][d] = sinv * (s - c * x) ----
  ws[OFF_H + l * 32 + j * 2 + 0] = (float)(sinvd * ((double)ss[l]       - c * x0_lo));
  ws[OFF_H + l * 32 + j * 2 + 1] = (float)(sinvd * ((double)ss[100 + l] - c * x1_lo));
  if (ahi < 100) {
    ws[OFF_H + ahi * 32 + j * 2 + 0] = (float)(sinvd * ((double)ss[ahi]       - c * x0_hi));
    ws[OFF_H + ahi * 32 + j * 2 + 1] = (float)(sinvd * ((double)ss[100 + ahi] - c * x1_hi));
  }
}

// =============================== K_TAIL ====================================
// 16 blocks x 256: stage h/Q^T/xl, Bc table, z = Bc*h, xt, intensity pairs.
// LDS float offsets:
#define L_H   0        // 3200
#define L_QT  3200     // 512
#define L_XL  3712     // 64
#define L_BC  3776     // 99*100 = 9900
#define L_Z   13676    // 99*32  = 3168
#define L_XT  16844    // 99*64  = 6336
#define L_PS  23180    // 4*64   = 256
#define L_TOT 23436    // * 4B = 93744 B

__global__ __launch_bounds__(256) void k_tail(
    const float* __restrict__ ls_in, const float* __restrict__ beta,
    const float* __restrict__ ws, float* __restrict__ out)
{
  extern __shared__ float lds[];
  const int tid = threadIdx.x;
  const float ls = ls_in[0];
  const float i2 = -0.5f / (ls * ls);

  // stage
  for (int e = tid; e < 3200; e += 256) lds[L_H + e] = ws[OFF_H + e];
  for (int e = tid; e < 512; e += 256)  lds[L_QT + e] = ws[OFF_QT + e];
  if (tid < 64) lds[L_XL + tid] = ws[OFF_XL + tid];
  for (int e = tid; e < NT * NBINS; e += 256) {
    int t = e / NBINS, p = e - t * NBINS;
    float tst = 1.0f + (float)t * (1.0f / 99.0f);
    float dd = tst - ((float)p + 0.5f) * 0.01f;
    lds[L_BC + e] = expf(dd * dd * i2);
  }
  __syncthreads();

  // z[t][j][d] = sum_p Bc[t][p] * h[p][j][d]
  for (int dot = tid; dot < NT * 32; dot += 256) {
    int t = dot >> 5, jd = dot & 31;
    float acc = 0.f;
    for (int p = 0; p < NBINS; ++p)
      acc += lds[L_BC + t * NBINS + p] * lds[L_H + p * 32 + jd];
    lds[L_Z + dot] = acc;
  }
  __syncthreads();

  // xt[t][n][d] = xl[nd] + trel * sum_j qt[j][n] * z[t][j][d]
  for (int e = tid; e < NT * 64; e += 256) {
    int t = e >> 6, nd = e & 63, n = nd >> 1, d = nd & 1;
    float acc = 0.f;
    for (int jq = 0; jq < 16; ++jq)
      acc += lds[L_QT + jq * 32 + n] * lds[L_Z + t * 32 + jq * 2 + d];
    float trel = (float)t * (1.0f / 99.0f);
    lds[L_XT + e] = lds[L_XL + nd] + trel * acc;
  }
  __syncthreads();

  // intensity: 64 pairs per block, 4-way t-split
  {
    const int pl = tid & 63, tc = tid >> 6;
    const int gp = blockIdx.x * 64 + pl;
    const int i = gp >> 5, jj = gp & 31;
    const float bsum = beta[i] + beta[jj];
    const int t0 = tc * 25, t1 = (t0 + 25 < NT) ? t0 + 25 : NT;
    float acc = 0.f;
    for (int t = t0; t < t1; ++t) {
      float2 xi = *(const float2*)&lds[L_XT + t * 64 + 2 * i];
      float2 xj = *(const float2*)&lds[L_XT + t * 64 + 2 * jj];
      float dx = xi.x - xj.x, dy = xi.y - xj.y;
      float sq = fmaxf(dx * dx + dy * dy, 1e-12f);
      acc += expf(bsum - sqrtf(sq));
    }
    lds[L_PS + tc * 64 + pl] = acc;
  }
  __syncthreads();
  if (tid < 64) {
    float s = lds[L_PS + tid] + lds[L_PS + 64 + tid]
            + lds[L_PS + 128 + tid] + lds[L_PS + 192 + tid];
    out[blockIdx.x * 64 + tid] = s * (1.0f / 99.0f);
  }
}

extern "C" void kernel_launch(void* const* d_in, const int* in_sizes, int n_in,
                              void* d_out, int out_size, void* d_ws, size_t ws_size,
                              hipStream_t stream) {
  const float* x0    = (const float*)d_in[0];
  const float* v     = (const float*)d_in[1];
  const float* beta  = (const float*)d_in[2];
  const float* sigma = (const float*)d_in[3];
  // d_in[4] = x0c: drops out (B_cross row 0 is zero)
  const float* ls    = (const float*)d_in[5];
  const float* Cq    = (const float*)d_in[6];
  float* out = (float*)d_out;
  float* ws  = (float*)d_ws;

  k2_all<<<16, 64, 0, stream>>>(x0, v, sigma, ls, Cq, ws);
  k_tail<<<16, 256, (size_t)L_TOT * sizeof(float), stream>>>(ls, beta, ws, out);
}

// Round 6
// 149.090 us; speedup vs baseline: 5.6137x; 1.5994x over previous
//
#include <hip/hip_runtime.h>
#include <math.h>

// Problem constants (reference: N=32, K=16, BINS=100, DIM=2, sample_size=100)
#define NBINS 100
#define NN    32
#define KD    16
#define NT    99    // sample_size-1

// ws float offsets
#define OFF_H   0        // h[p][j][d] 100*16*2 = 3200
#define OFF_QT  3200     // qt[j][n] = Q[n][j]  16*32 = 512
#define OFF_XL  3712     // x_last 64
#define OFF_C   3776     // c_j = sigma^-2 * mu_j (16)
#define OFF_P   3792     // [0]=sigma_sq_inv

// ---------------- f64 cross-lane primitives (VALU-only, no DS) -------------
template<int CTRL>
__device__ __forceinline__ double dmov_dpp(double x) {
  union { double d; int i[2]; } u, r;
  u.d = x;
  r.i[0] = __builtin_amdgcn_update_dpp(0, u.i[0], CTRL, 0xf, 0xf, true);
  r.i[1] = __builtin_amdgcn_update_dpp(0, u.i[1], CTRL, 0xf, 0xf, true);
  return r.d;
}
__device__ __forceinline__ double drdlane(double x, int lane) {
  union { double d; int i[2]; } u;
  u.d = x;
  u.i[0] = __builtin_amdgcn_readlane(u.i[0], lane);
  u.i[1] = __builtin_amdgcn_readlane(u.i[1], lane);
  return u.d;
}
// sum of 64 lanes for 3 values, result broadcast to all lanes.
// row_shr prefix (1,2,4,8) -> row sums in lanes 15/31/47/63; bcast15+bcast31
// accumulate into lane 63; readlane 63 broadcasts.
__device__ __forceinline__ void dsum3(double& a, double& b, double& c) {
  a += dmov_dpp<0x111>(a); b += dmov_dpp<0x111>(b); c += dmov_dpp<0x111>(c);
  a += dmov_dpp<0x112>(a); b += dmov_dpp<0x112>(b); c += dmov_dpp<0x112>(c);
  a += dmov_dpp<0x114>(a); b += dmov_dpp<0x114>(b); c += dmov_dpp<0x114>(c);
  a += dmov_dpp<0x118>(a); b += dmov_dpp<0x118>(b); c += dmov_dpp<0x118>(c);
  a += dmov_dpp<0x142>(a); b += dmov_dpp<0x142>(b); c += dmov_dpp<0x142>(c);
  a += dmov_dpp<0x143>(a); b += dmov_dpp<0x143>(b); c += dmov_dpp<0x143>(c);
  a = drdlane(a, 63); b = drdlane(b, 63); c = drdlane(c, 63);
}
// whole-wave shift-up-by-1: out[l] = in[l-1], out[0] = c0  (row_shr:1 + fixups)
__device__ __forceinline__ double dshup(double x, double c0, int lane) {
  double v = dmov_dpp<0x111>(x);
  double x15 = drdlane(x, 15), x31 = drdlane(x, 31), x47 = drdlane(x, 47);
  v = (lane == 0)  ? c0  : v;
  v = (lane == 16) ? x15 : v;
  v = (lane == 32) ? x31 : v;
  v = (lane == 48) ? x47 : v;
  return v;
}

// ====================== K0: eig(C^T C) + Q + params ========================
// 256 threads. xor-pair tournament (mask m = 1..15 covers all 120 pairs),
// 5 sweeps, 3 barriers/round, no integer mods. Also x_last.
__global__ __launch_bounds__(256) void k0_eig(
    const float* __restrict__ x0, const float* __restrict__ v,
    const float* __restrict__ sigma_in, const float* __restrict__ Cq,
    float* __restrict__ ws)
{
  __shared__ double A[16][17], Vv[16][17];
  __shared__ double csC[8], csS[8];
  __shared__ float CqS[NN * KD];
  const int tid = threadIdx.x;
  float sig = fmaxf(sigma_in[0], 0.05f);          // clip(sigma, 5/BINS)
  const double sinvd = 1.0 / ((double)sig * (double)sig);

  if (tid < 64) {                                  // x_last
    float acc = 0.f;
    for (int p = 0; p < NBINS; ++p) acc += v[p * 64 + tid];
    ws[OFF_XL + tid] = x0[tid] + 0.01f * acc;
  }
  for (int e = tid; e < NN * KD; e += 256) CqS[e] = Cq[e];
  __syncthreads();

  {                                                // G = Cq^T Cq, V = I
    int k1 = tid >> 4, k2 = tid & 15;
    double acc = 0.0;
    for (int n = 0; n < NN; ++n)
      acc += (double)CqS[n * 16 + k1] * (double)CqS[n * 16 + k2];
    A[k1][k2] = acc;
    Vv[k1][k2] = (k1 == k2) ? 1.0 : 0.0;
  }
  __syncthreads();

  for (int sweep = 0; sweep < 5; ++sweep)
  for (int m = 1; m <= 15; ++m) {
    const int hb = 31 - __clz(m);
    const int lowm = (1 << hb) - 1;
    if (tid < 8) {                                 // c,s per pair
      int p = ((tid & ~lowm) << 1) | (tid & lowm), q = p ^ m;
      double app = A[p][p], aqq = A[q][q], apq = A[p][q];
      double c = 1.0, s = 0.0;
      if (fabs(apq) > 1e-300) {
        double th = (aqq - app) / (2.0 * apq);
        double t_ = ((th >= 0.0) ? 1.0 : -1.0) / (fabs(th) + sqrt(th * th + 1.0));
        c = 1.0 / sqrt(t_ * t_ + 1.0);
        s = t_ * c;
      }
      csC[tid] = c; csS[tid] = s;
    }
    __syncthreads();
    {                                              // rows of A ; V columns
      int half = tid >> 7, it = tid & 127, t = it >> 4, rc = it & 15;
      int p = ((t & ~lowm) << 1) | (t & lowm), q = p ^ m;
      double c = csC[t], s = csS[t];
      if (half == 0) {
        double ap = A[p][rc], aq = A[q][rc];
        A[p][rc] = c * ap - s * aq;
        A[q][rc] = s * ap + c * aq;
      } else {
        double vp = Vv[rc][p], vq = Vv[rc][q];
        Vv[rc][p] = c * vp - s * vq;
        Vv[rc][q] = s * vp + c * vq;
      }
    }
    __syncthreads();
    if (tid < 128) {                               // columns of A
      int t = tid >> 4, rc = tid & 15;
      int p = ((t & ~lowm) << 1) | (t & lowm), q = p ^ m;
      double c = csC[t], s = csS[t];
      double ap = A[rc][p], aq = A[rc][q];
      A[rc][p] = c * ap - s * aq;
      A[rc][q] = s * ap + c * aq;
    }
    __syncthreads();
  }

  if (tid < 16) {
    double mu = A[tid][tid];
    if (mu < 0.0) mu = 0.0;
    ws[OFF_C + tid] = (float)(sinvd * mu);
  }
  if (tid == 0) ws[OFF_P + 0] = (float)sinvd;
  for (int e = tid; e < 512; e += 256) {           // QT[j][n] = (C*U)[n][j]
    int jq = e >> 5, n = e & 31;
    double acc = 0.0;
    for (int k2 = 0; k2 < 16; ++k2)
      acc += (double)CqS[n * 16 + k2] * Vv[k2][jq];
    ws[OFF_QT + e] = (float)acc;
  }
}

// ============== K1: per-eigenvalue Toeplitz solve (DS-free Levinson) =======
// 16 blocks x 1 wave. h_j = sinv * (I + c_j*Btail)^-1 s_j  (RHS = s directly).
// Whole recursion in registers; reductions via DPP; gathers via readlane.
__global__ __launch_bounds__(64) void k1_lev(
    const float* __restrict__ v, const float* __restrict__ ls_in,
    float* __restrict__ ws)
{
  __shared__ float vT[64 * 101];                   // vT[nd][p]
  __shared__ float qs[32];
  const int l = threadIdx.x;
  const int j = blockIdx.x;
  const double c = (double)ws[OFF_C + j];
  const double sinvd = (double)ws[OFF_P + 0];
  const float ls = ls_in[0];
  const float i2 = -0.5f / (ls * ls);
  const int ahi = 64 + l;

  for (int p = 0; p < NBINS; ++p) vT[l * 101 + p] = v[p * 64 + l];
  if (l < 32) qs[l] = ws[OFF_QT + j * 32 + l];
  __syncthreads();

  // s at p = l (lo) and p = 64+l (hi): conflict-free lane-contiguous reads
  float s0l = 0.f, s1l = 0.f, s0h = 0.f, s1h = 0.f;
  for (int n = 0; n < NN; ++n) {
    float qv = qs[n];
    s0l += qv * vT[(2 * n) * 101 + l];
    s1l += qv * vT[(2 * n + 1) * 101 + l];
    if (ahi < 100) {
      s0h += qv * vT[(2 * n) * 101 + ahi];
      s1h += qv * vT[(2 * n + 1) * 101 + ahi];
    }
  }

  const double m0  = 1.0 + c * (1.0 + 1e-5);
  const double im0 = 1.0 / m0;
  float gl = expf((0.01f * (float)l) * (0.01f * (float)l) * i2);
  float gh = expf((0.01f * (float)ahi) * (0.01f * (float)ahi) * i2);
  double rho_lo = (l == 0) ? 1.0 : c * (double)gl * im0;
  double rho_hi = (ahi < 100) ? c * (double)gh * im0 : 0.0;
  double b0_lo = (double)s0l * im0, b1_lo = (double)s1l * im0;
  double b0_hi = (ahi < 100) ? (double)s0h * im0 : 0.0;
  double b1_hi = (ahi < 100) ? (double)s1h * im0 : 0.0;

  double rho1 = drdlane(rho_lo, 1);
  double bb00 = drdlane(b0_lo, 0), bb10 = drdlane(b1_lo, 0);
  double x0_lo = (l == 0) ? bb00 : 0.0, x0_hi = 0.0;
  double x1_lo = (l == 0) ? bb10 : 0.0, x1_hi = 0.0;
  double y_lo  = (l == 0) ? -rho1 : 0.0, y_hi = 0.0;
  double yr_lo = (l == 0) ? -rho1 : 0.0, yr_hi = 0.0;
  double rr_lo = (l == 0) ?  rho1 : 0.0, rr_hi = 0.0;
  double alpha = -rho1, betav = 1.0;

  for (int k = 1; k < 100; ++k) {
    betav *= (1.0 - alpha * alpha);
    double ib = 1.0 / betav;
    const bool lo_on = (l < k);
    const bool hi_on = (ahi < k);
    double px0 = (lo_on ? rr_lo * x0_lo : 0.0) + (hi_on ? rr_hi * x0_hi : 0.0);
    double px1 = (lo_on ? rr_lo * x1_lo : 0.0) + (hi_on ? rr_hi * x1_hi : 0.0);
    double py  = (lo_on ? rr_lo * y_lo  : 0.0) + (hi_on ? rr_hi * y_hi  : 0.0);
    dsum3(px0, px1, py);                           // VALU-only reduce+bcast
    double bk0 = (k < 64) ? drdlane(b0_lo, k) : drdlane(b0_hi, k - 64);
    double bk1 = (k < 64) ? drdlane(b1_lo, k) : drdlane(b1_hi, k - 64);
    double rk1 = 0.0;
    if (k < 99)
      rk1 = (k + 1 < 64) ? drdlane(rho_lo, k + 1) : drdlane(rho_hi, k - 63);
    double mu0 = (bk0 - px0) * ib;
    double mu1 = (bk1 - px1) * ib;
    double an  = -(rk1 + py) * ib;
    double w_lo = yr_lo + an * y_lo;
    double w_hi = yr_hi + an * y_hi;
    if (lo_on) { x0_lo += mu0 * yr_lo; x1_lo += mu1 * yr_lo; y_lo += an * yr_lo; }
    if (hi_on) { x0_hi += mu0 * yr_hi; x1_hi += mu1 * yr_hi; y_hi += an * yr_hi; }
    if (k < 64) { if (l == k)      { x0_lo = mu0; x1_lo = mu1; y_lo = an; } }
    else        { if (l == k - 64) { x0_hi = mu0; x1_hi = mu1; y_hi = an; } }
    double w63 = drdlane(w_lo, 63);
    yr_lo = dshup(w_lo, an, l);
    yr_hi = dshup(w_hi, w63, l);
    double r63 = drdlane(rr_lo, 63);
    rr_lo = dshup(rr_lo, rk1, l);
    rr_hi = dshup(rr_hi, r63, l);
    alpha = an;
  }

  // h[p][j][d] = sinv * x[p]
  ws[OFF_H + l * 32 + j * 2 + 0] = (float)(sinvd * x0_lo);
  ws[OFF_H + l * 32 + j * 2 + 1] = (float)(sinvd * x1_lo);
  if (ahi < 100) {
    ws[OFF_H + ahi * 32 + j * 2 + 0] = (float)(sinvd * x0_hi);
    ws[OFF_H + ahi * 32 + j * 2 + 1] = (float)(sinvd * x1_hi);
  }
}

// =============================== K_TAIL ====================================
// 16 blocks x 256: stage h/Q^T/xl, Bc table, z = Bc*h, xt, intensity pairs.
#define L_H   0        // 3200
#define L_QT  3200     // 512
#define L_XL  3712     // 64
#define L_BC  3776     // 99*100 = 9900
#define L_Z   13676    // 99*32  = 3168
#define L_XT  16844    // 99*64  = 6336
#define L_PS  23180    // 4*64   = 256
#define L_TOT 23436

__global__ __launch_bounds__(256) void k_tail(
    const float* __restrict__ ls_in, const float* __restrict__ beta,
    const float* __restrict__ ws, float* __restrict__ out)
{
  extern __shared__ float lds[];
  const int tid = threadIdx.x;
  const float ls = ls_in[0];
  const float i2 = -0.5f / (ls * ls);

  for (int e = tid; e < 3200; e += 256) lds[L_H + e] = ws[OFF_H + e];
  for (int e = tid; e < 512; e += 256)  lds[L_QT + e] = ws[OFF_QT + e];
  if (tid < 64) lds[L_XL + tid] = ws[OFF_XL + tid];
  for (int e = tid; e < NT * NBINS; e += 256) {
    int t = e / NBINS, p = e - t * NBINS;
    float tst = 1.0f + (float)t * (1.0f / 99.0f);
    float dd = tst - ((float)p + 0.5f) * 0.01f;
    lds[L_BC + e] = expf(dd * dd * i2);
  }
  __syncthreads();

  // z[t][j][d] = sum_p Bc[t][p] * h[p][j][d]
  for (int dot = tid; dot < NT * 32; dot += 256) {
    int t = dot >> 5, jd = dot & 31;
    float acc = 0.f;
    for (int p = 0; p < NBINS; ++p)
      acc += lds[L_BC + t * NBINS + p] * lds[L_H + p * 32 + jd];
    lds[L_Z + dot] = acc;
  }
  __syncthreads();

  // xt[t][n][d] = xl[nd] + trel * sum_j qt[j][n] * z[t][j][d]
  for (int e = tid; e < NT * 64; e += 256) {
    int t = e >> 6, nd = e & 63, n = nd >> 1, d = nd & 1;
    float acc = 0.f;
    for (int jq = 0; jq < 16; ++jq)
      acc += lds[L_QT + jq * 32 + n] * lds[L_Z + t * 32 + jq * 2 + d];
    float trel = (float)t * (1.0f / 99.0f);
    lds[L_XT + e] = lds[L_XL + nd] + trel * acc;
  }
  __syncthreads();

  // intensity: 64 pairs per block, 4-way t-split
  {
    const int pl = tid & 63, tc = tid >> 6;
    const int gp = blockIdx.x * 64 + pl;
    const int i = gp >> 5, jj = gp & 31;
    const float bsum = beta[i] + beta[jj];
    const int t0 = tc * 25, t1 = (t0 + 25 < NT) ? t0 + 25 : NT;
    float acc = 0.f;
    for (int t = t0; t < t1; ++t) {
      float2 xi = *(const float2*)&lds[L_XT + t * 64 + 2 * i];
      float2 xj = *(const float2*)&lds[L_XT + t * 64 + 2 * jj];
      float dx = xi.x - xj.x, dy = xi.y - xj.y;
      float sq = fmaxf(dx * dx + dy * dy, 1e-12f);
      acc += expf(bsum - sqrtf(sq));
    }
    lds[L_PS + tc * 64 + pl] = acc;
  }
  __syncthreads();
  if (tid < 64) {
    float s = lds[L_PS + tid] + lds[L_PS + 64 + tid]
            + lds[L_PS + 128 + tid] + lds[L_PS + 192 + tid];
    out[blockIdx.x * 64 + tid] = s * (1.0f / 99.0f);
  }
}

extern "C" void kernel_launch(void* const* d_in, const int* in_sizes, int n_in,
                              void* d_out, int out_size, void* d_ws, size_t ws_size,
                              hipStream_t stream) {
  const float* x0    = (const float*)d_in[0];
  const float* v     = (const float*)d_in[1];
  const float* beta  = (const float*)d_in[2];
  const float* sigma = (const float*)d_in[3];
  // d_in[4] = x0c: unused (B_cross row 0 is zero)
  const float* ls    = (const float*)d_in[5];
  const float* Cq    = (const float*)d_in[6];
  float* out = (float*)d_out;
  float* ws  = (float*)d_ws;

  k0_eig<<<1, 256, 0, stream>>>(x0, v, sigma, Cq, ws);
  k1_lev<<<16, 64, 0, stream>>>(v, ls, ws);
  k_tail<<<16, 256, (size_t)L_TOT * sizeof(float), stream>>>(ls, beta, ws, out);
}